// Round 14
// baseline (4916.114 us; speedup 1.0000x reference)
//
#include <hip/hip_runtime.h>
#include <hip/hip_cooperative_groups.h>
#include <math.h>

#define BB 32
#define TT 64
#define INPW 90
#define NU 4
#define NH1 2048
#define NHC 1024
#define NHD 1024
#define NZ 512
// barrier slot: 16 sub-counters @ 2KB stride, master @ 16*2KB, 8 release flags @ (17+k)*2KB
#define BSTRIDE 12800  // u32 per slot (25 * 512)

typedef unsigned short u16;
typedef __attribute__((ext_vector_type(8))) short short8;
typedef __attribute__((ext_vector_type(4))) float f32x4;
typedef __attribute__((ext_vector_type(4))) unsigned uv4;
typedef __attribute__((ext_vector_type(2))) unsigned uv2;

__device__ __forceinline__ float sigf(float v) { return 1.0f / (1.0f + __expf(-v)); }

__device__ __forceinline__ u16 f2bf(float f) {
  unsigned u = __float_as_uint(f);
  unsigned r = (u + 0x7FFFu + ((u >> 16) & 1u)) >> 16;
  return (u16)r;
}
__device__ __forceinline__ float bf2f(u16 b) { return __uint_as_float(((unsigned)b) << 16); }

// ---- coherence helpers (cross-XCD, no cache flush) ----
__device__ __forceinline__ void cstore8(u16* p, uv2 v) {
  asm volatile("global_store_dwordx2 %0, %1, off sc0 sc1" :: "v"(p), "v"(v) : "memory");
}
__device__ __forceinline__ void cstore4(unsigned* p, unsigned v) {
  asm volatile("global_store_dword %0, %1, off sc0 sc1" :: "v"(p), "v"(v) : "memory");
}
__device__ __forceinline__ unsigned fload(const unsigned* p) {
  unsigned r;
  asm volatile("global_load_dword %0, %1, off sc0 sc1\n\ts_waitcnt vmcnt(0)"
               : "=v"(r) : "v"(p) : "memory");
  return r;
}
// channel-spread two-level barrier, one-shot per slot; 256 blocks.
__device__ __forceinline__ void gbar(unsigned* base) {
  asm volatile("s_waitcnt vmcnt(0)" ::: "memory");
  __syncthreads();
  if (threadIdx.x == 0) {
    unsigned old = atomicAdd(&base[(blockIdx.x & 15) * 512], 1u);
    if (old == 15u) {
      unsigned m = atomicAdd(&base[16 * 512], 1u);
      if (m == 15u) {
#pragma unroll
        for (int k = 0; k < 8; ++k) cstore4(&base[(17 + k) * 512], 1u);
        asm volatile("s_waitcnt vmcnt(0)" ::: "memory");
      }
    }
    while (!fload(&base[(17 + (blockIdx.x & 7)) * 512])) __builtin_amdgcn_s_sleep(2);
  }
  __syncthreads();
}

// async global->LDS, 16B per lane
__device__ __forceinline__ void gload16(const u16* g, u16* l) {
  __builtin_amdgcn_global_load_lds(
      (const __attribute__((address_space(1))) unsigned*)g,
      (__attribute__((address_space(3))) unsigned*)l, 16, 0, 0);
}

// ---------------- conversion kernels ----------------
struct CvtJobs { const float* s[12]; u16* d[12]; long n[12]; int cnt; };
__global__ void cvt_multi(CvtJobs J) {
  long stride = (long)gridDim.x * 256 * 4;
  for (int j = 0; j < J.cnt; ++j) {
    const float* s = J.s[j]; u16* d = J.d[j]; long n = J.n[j];
    for (long i = ((long)blockIdx.x * 256 + threadIdx.x) * 4; i < n; i += stride) {
      float4 v = *(const float4*)&s[i];
      d[i] = f2bf(v.x); d[i + 1] = f2bf(v.y); d[i + 2] = f2bf(v.z); d[i + 3] = f2bf(v.w);
    }
  }
}

struct BPJobs { const float* s[5]; float* d[5]; int H[5]; int cnt; };
__global__ void bias_perm5(BPJobs J) {
  for (int j = 0; j < J.cnt; ++j) {
    int tot = 4 * J.H[j];
    for (int n = blockIdx.x * 256 + threadIdx.x; n < tot; n += gridDim.x * 256)
      J.d[j][n] = J.s[j][(long)(n & 3) * J.H[j] + (n >> 2)];
  }
}

__global__ void cvt_pad(const float* __restrict__ s, int sld, int cols,
                        u16* __restrict__ d, int dld, int rows) {
  int c = blockIdx.x * blockDim.x + threadIdx.x;
  int r = blockIdx.y;
  if (c >= dld) return;
  d[(long)r * dld + c] = (c < cols) ? f2bf(s[(long)r * sld + c]) : (u16)0;
}

// gate-interleaved row permutation: dst row r <- src row (r&3)*H + (r>>2)
__global__ void cvt_permrow(const float* __restrict__ s, int sld, int cols,
                            u16* __restrict__ d, int dld, int H) {
  int c = blockIdx.x * blockDim.x + threadIdx.x;
  int r = blockIdx.y;
  if (c >= dld) return;
  long sr = (long)(r & 3) * H + (r >> 2);
  d[(long)r * dld + c] = (c < cols) ? f2bf(s[sr * sld + c]) : (u16)0;
}

__global__ void xcvt(const float* __restrict__ x, u16* __restrict__ xb) {
  int r = blockIdx.x, c = threadIdx.x;
  int b = r & 31, t = r >> 5;
  float v = (c < INPW) ? x[((long)b * TT + t) * INPW + c] : 0.0f;
  xb[(long)r * 128 + c] = f2bf(v);
}

__global__ void w4t_k(const float* __restrict__ w4, u16* __restrict__ w4tb) {
  int k = blockIdx.x, n = threadIdx.x;
  w4tb[(long)k * 128 + n] = (n < INPW) ? f2bf(w4[(long)n * NHD + k]) : (u16)0;
}

__global__ void bfuse_k(const float* __restrict__ d1_wih, const float* __restrict__ b4,
                        float* __restrict__ bfuse) {
  int r = blockIdx.x * 256 + threadIdx.x;
  if (r >= 4096) return;
  float s = 0.0f;
  for (int n = 0; n < INPW; ++n) s += d1_wih[(long)r * 1114 + 1024 + n] * b4[n];
  bfuse[r] = s;
}

// ---------------- bf16 MFMA GEMM: global_load_lds dbuf, XCD-aware 1D grid ----------------
// mode 0: C[m*ldc+n]
// mode 1 (enc xp): dst = (((m>>5)*256+(n>>5))*32+(m&31))*32 + (n&31)
// mode 2 (dec xeb): dst = ((n>>4)*128+m)*16 + (n&15)
__global__ __launch_bounds__(256) void gemm_bf(
    const u16* __restrict__ A, int lda, const u16* __restrict__ Bw, int ldb,
    const float* __restrict__ bias, u16* __restrict__ C, int ldc, int K, int mode,
    int nbm, int nbn) {
  __shared__ u16 Asm[2][128 * 64];
  __shared__ u16 Bsm[2][128 * 64];
  const int tid = threadIdx.x;
  const int w = tid >> 6, l = tid & 63, q = (tid >> 4) & 3, ln = tid & 15;
  const int wm = w & 1, wn = w >> 1;
  int fid = blockIdx.x;
  int sidx = fid >> 3, xcd = fid & 7;
  int bm, bn;
  if ((nbm & 7) == 0) { bn = sidx % nbn; bm = xcd * (nbm >> 3) + sidx / nbn; }
  else if ((nbn & 7) == 0) { bm = sidx % nbm; bn = xcd * (nbn >> 3) + sidx / nbm; }
  else { bm = fid % nbm; bn = fid / nbm; }
  const long am0 = (long)bm * 128;
  const long bn0 = (long)bn * 128;
  const u16* Ap0 = A + am0 * lda;
  const u16* Bp0 = Bw + bn0 * ldb;
  f32x4 acc[4][4] = {};

  auto stage = [&](int b, int k0) {
#pragma unroll
    for (int i = 0; i < 4; ++i) {
      int row = (w * 4 + i) * 8 + (l >> 3);
      int col = (((l & 7) ^ (row & 7)) << 3) + k0;
      gload16(Ap0 + (long)row * lda + col, &Asm[b][(w * 4 + i) * 512]);
      gload16(Bp0 + (long)row * ldb + col, &Bsm[b][(w * 4 + i) * 512]);
    }
  };

  const int kt = K >> 6;
  stage(0, 0);
  asm volatile("s_waitcnt vmcnt(0)" ::: "memory");
  __syncthreads();
  int buf = 0;
  for (int t = 0; t < kt; ++t) {
    if (t + 1 < kt) stage(buf ^ 1, (t + 1) << 6);
#pragma unroll
    for (int kh = 0; kh < 2; ++kh) {
      short8 af[4], bg[4];
#pragma unroll
      for (int tt2 = 0; tt2 < 4; ++tt2) {
        int arr = wm * 64 + tt2 * 16 + ln;
        af[tt2] = *(short8*)&Asm[buf][arr * 64 + (((q + 4 * kh) ^ (arr & 7)) << 3)];
        int brr = wn * 64 + tt2 * 16 + ln;
        bg[tt2] = *(short8*)&Bsm[buf][brr * 64 + (((q + 4 * kh) ^ (brr & 7)) << 3)];
      }
#pragma unroll
      for (int mt = 0; mt < 4; ++mt)
#pragma unroll
        for (int nt = 0; nt < 4; ++nt)
          acc[mt][nt] = __builtin_amdgcn_mfma_f32_16x16x32_bf16(af[mt], bg[nt], acc[mt][nt], 0, 0, 0);
    }
    asm volatile("s_waitcnt vmcnt(0)" ::: "memory");
    __syncthreads();
    buf ^= 1;
  }
#pragma unroll
  for (int nt = 0; nt < 4; ++nt) {
    long n = bn0 + wn * 64 + nt * 16 + ln;
    float bv = bias ? bias[n] : 0.0f;
#pragma unroll
    for (int mt = 0; mt < 4; ++mt) {
#pragma unroll
      for (int r = 0; r < 4; ++r) {
        long m = am0 + wm * 64 + mt * 16 + (q << 2) + r;
        long dst;
        if (mode == 0) {
          dst = m * ldc + n;
        } else if (mode == 1) {
          dst = (((m >> 5) * 256 + (n >> 5)) * 32 + (m & 31)) * 32 + (n & 31);
        } else {
          dst = ((n >> 4) * 128 + m) * 16 + (n & 15);
        }
        C[dst] = f2bf(acc[mt][nt][r] + bv);
      }
    }
  }
}

// ---------------- fp32 GEMM (tvec / sall) ----------------
__global__ __launch_bounds__(256) void gemm128(
    const float* __restrict__ A, int lda, const float* __restrict__ W, int ldw,
    const float* __restrict__ bias, float* __restrict__ C, int ldc,
    int M, int K, int act, u16* __restrict__ Cb) {
  __shared__ float As[16][132];
  __shared__ float Bs[16][132];
  const int tid = threadIdx.x;
  const int bm = blockIdx.x, bn = blockIdx.y;
  const int tm = tid & 15, tn = tid >> 4;
  float acc[8][8] = {};
  for (int k0 = 0; k0 < K; k0 += 16) {
#pragma unroll
    for (int it = 0; it < 2; ++it) {
      int e = it * 256 + tid;
      int r = e >> 2, c4 = (e & 3) * 4;
      int m = bm * 128 + r;
      float4 v = make_float4(0.f, 0.f, 0.f, 0.f);
      if (m < M) v = *(const float4*)&A[(long)m * lda + k0 + c4];
      As[c4 + 0][r] = v.x; As[c4 + 1][r] = v.y; As[c4 + 2][r] = v.z; As[c4 + 3][r] = v.w;
      int n = bn * 128 + r;
      float4 w = *(const float4*)&W[(long)n * ldw + k0 + c4];
      Bs[c4 + 0][r] = w.x; Bs[c4 + 1][r] = w.y; Bs[c4 + 2][r] = w.z; Bs[c4 + 3][r] = w.w;
    }
    __syncthreads();
#pragma unroll
    for (int kk = 0; kk < 16; ++kk) {
      float4 a0 = *(const float4*)&As[kk][tm * 8];
      float4 a1 = *(const float4*)&As[kk][tm * 8 + 4];
      float4 b0 = *(const float4*)&Bs[kk][tn * 8];
      float4 b1 = *(const float4*)&Bs[kk][tn * 8 + 4];
      float av[8] = {a0.x, a0.y, a0.z, a0.w, a1.x, a1.y, a1.z, a1.w};
      float bv[8] = {b0.x, b0.y, b0.z, b0.w, b1.x, b1.y, b1.z, b1.w};
#pragma unroll
      for (int i = 0; i < 8; ++i)
#pragma unroll
        for (int j = 0; j < 8; ++j)
          acc[i][j] += av[i] * bv[j];
    }
    __syncthreads();
  }
#pragma unroll
  for (int i = 0; i < 8; ++i) {
    int m = bm * 128 + tm * 8 + i;
    if (m >= M) continue;
#pragma unroll
    for (int j = 0; j < 8; ++j) {
      int n = bn * 128 + tn * 8 + j;
      float v = acc[i][j] + bias[n];
      if (act == 1) v = tanhf(v);
      else if (act == 2) v = log1pf(__expf(v));
      C[(long)m * ldc + n] = v;
      if (Cb) Cb[(long)m * ldc + n] = f2bf(v);
    }
  }
}

// ---------------- latent head ----------------
__global__ __launch_bounds__(256) void latgemm(
    const float* __restrict__ A, const float* __restrict__ W,
    const float* __restrict__ bias, float* __restrict__ C, int act) {
  __shared__ float red[16][16][32];
  const int tid = threadIdx.x;
  const int c = tid & 15, ksl = tid >> 4;
  const int n = blockIdx.x * 16 + c;
  const float* wp = W + (long)n * 4096 + ksl * 256;
  const float* ap = A + ksl * 256;
  float acc[32];
#pragma unroll
  for (int r = 0; r < 32; ++r) acc[r] = 0.f;
  for (int k = 0; k < 256; k += 4) {
    float4 wv = *(const float4*)(wp + k);
#pragma unroll
    for (int r = 0; r < 32; ++r) {
      float4 hv = *(const float4*)(ap + (long)r * 4096 + k);
      acc[r] += hv.x * wv.x + hv.y * wv.y + hv.z * wv.z + hv.w * wv.w;
    }
  }
#pragma unroll
  for (int r = 0; r < 32; ++r) red[ksl][c][r] = acc[r];
  __syncthreads();
  for (int o = tid; o < 512; o += 256) {
    int cc = o >> 5, r = o & 31;
    float s = 0.f;
#pragma unroll
    for (int p = 0; p < 16; ++p) s += red[p][cc][r];
    s += bias[blockIdx.x * 16 + cc];
    if (act == 2) s = log1pf(__expf(s));
    C[(long)r * 512 + blockIdx.x * 16 + cc] = s;
  }
}

__global__ void zcalc_kernel(const float* __restrict__ zm, const float* __restrict__ zs,
                             const float* __restrict__ eps, float* __restrict__ z) {
  int e = blockIdx.x * 256 + threadIdx.x;
  if (e < BB * NZ) z[e] = zm[e] + eps[e] * zs[e];
}

__global__ void softmax_kernel(float* __restrict__ out) {
  long row = blockIdx.x;
  float* p = out + row * INPW;
  int lane = threadIdx.x;
  float v0 = (lane < INPW) ? p[lane] : -1e30f;
  float v1 = (lane + 64 < INPW) ? p[lane + 64] : -1e30f;
  float m = fmaxf(v0, v1);
#pragma unroll
  for (int off = 32; off > 0; off >>= 1) m = fmaxf(m, __shfl_xor(m, off));
  float e0 = (lane < INPW) ? __expf(v0 - m) : 0.0f;
  float e1 = (lane + 64 < INPW) ? __expf(v1 - m) : 0.0f;
  float sum = e0 + e1;
#pragma unroll
  for (int off = 32; off > 0; off >>= 1) sum += __shfl_xor(sum, off);
  float inv = 1.0f / sum;
  if (lane < INPW) p[lane] = e0 * inv;
  if (lane + 64 < INPW) p[lane + 64] = e1 * inv;
}

// ---------------- persistent encoder: LDS weights, dirs sequential ----------------
struct EncArgs {
  const u16* whh[2];
  const u16* xp[2];
  const float* bhh[2];
  u16* y0b;
  u16* h1a[2];
  float* htb;
  unsigned* bar;
  int layer;
};

__global__ __launch_bounds__(512) void enc_coop(EncArgs A) {
  __shared__ u16 Wl[2 * 64 * 64 * 8];
  __shared__ __align__(16) float red[4 * 64 * 4];
  const int tid = threadIdx.x;
  const int w = tid >> 6, l = tid & 63;
  const int rt = w & 1, bh = (w >> 1) & 1, kh = w >> 2;
  const int kg = l >> 4, b0 = l & 15;
  const int j0 = blockIdx.x * 8;
  const int jout = j0 + rt * 4 + kg;
  const int batch = bh * 16 + b0;
  float* redp = &red[((bh * 2 + rt) * 64 + l) * 4];

  for (int dir = 0; dir < 2; ++dir) {
    __syncthreads();
    {
      const u16* W = A.whh[dir];
      for (int e = tid; e < 8192; e += 512) {
        int ert = e >> 12, es = (e >> 6) & 63, el = e & 63;
        int etr = el & 15;
        long gr = (long)(etr & 3) * 2048 + j0 + ert * 4 + (etr >> 2);
        *(uint4*)&Wl[((ert * 64 + es) * 64 + el) * 8] =
            *(const uint4*)&W[gr * 2048 + (el >> 4) * 8 + (long)es * 32];
      }
    }
    __syncthreads();
    const float* bhh = A.bhh[dir];
    const u16* xp = A.xp[dir];
    const float bi0 = bhh[jout], bi1 = bhh[2048 + jout],
                bi2 = bhh[4096 + jout], bi3 = bhh[6144 + jout];
    float creg = 0.f;
    ushort4 xv4 = make_ushort4(0, 0, 0, 0);
    if (kh == 0) {
      int tt0 = dir ? 63 : 0;
      xv4 = *(const ushort4*)(xp + ((((long)tt0 * 256 + blockIdx.x) * 32 + batch) * 32)
                              + (rt * 4 + kg) * 4);
    }
    for (int s = 0; s < 64; ++s) {
      if (s) gbar(A.bar + (long)(dir * 63 + (s - 1)) * BSTRIDE);
      const int tt = dir ? 63 - s : s;
      f32x4 acc = {0.f, 0.f, 0.f, 0.f};
      if (s) {
        const u16* hb; long hld;
        if (A.layer == 0) {
          int tp = dir ? tt + 1 : tt - 1;
          hb = A.y0b + (long)tp * 32 * 4096 + dir * 2048;
          hld = 4096;
        } else {
          hb = A.h1a[dir] + (long)(s - 1) * 32 * 2048;
          hld = 2048;
        }
        const u16* xv = hb + (long)batch * hld + kg * 8;
        for (int ks = kh * 32; ks < kh * 32 + 32; ks += 8) {
          uint4 bv[8]; short8 av[8];
#pragma unroll
          for (int uu = 0; uu < 8; ++uu)
            bv[uu] = *(const uint4*)(xv + (long)(ks + uu) * 32);
#pragma unroll
          for (int uu = 0; uu < 8; ++uu)
            av[uu] = *(const short8*)&Wl[((rt * 64 + ks + uu) * 64 + l) * 8];
#pragma unroll
          for (int uu = 0; uu < 8; ++uu)
            acc = __builtin_amdgcn_mfma_f32_16x16x32_bf16(av[uu], *(short8*)&bv[uu], acc, 0, 0, 0);
        }
      }
      if (kh) *(f32x4*)redp = acc;
      __syncthreads();
      if (kh == 0) {
        f32x4 o = *(f32x4*)redp;
        float g0 = acc[0] + o[0] + bi0 + bf2f(xv4.x);
        float g1 = acc[1] + o[1] + bi1 + bf2f(xv4.y);
        float g2 = acc[2] + o[2] + bi2 + bf2f(xv4.z);
        float g3 = acc[3] + o[3] + bi3 + bf2f(xv4.w);
        float iv = sigf(g0), fv = sigf(g1), gv = tanhf(g2), ov = sigf(g3);
        float c = fv * creg + iv * gv;
        creg = c;
        float h = ov * tanhf(c);
        if (A.layer == 1 && s == 63) A.htb[batch * 4096 + dir * 2048 + jout] = h;
        // shuffle-packed 8B coherent h-store (lanes<16 per wave)
        unsigned hbits = f2bf(h);
        unsigned p0 = __shfl((int)hbits, (l & 15));
        unsigned p1 = __shfl((int)hbits, (l & 15) + 16);
        unsigned p2 = __shfl((int)hbits, (l & 15) + 32);
        unsigned p3 = __shfl((int)hbits, (l & 15) + 48);
        if (l < 16) {
          int b2 = bh * 16 + l;
          uv2 v;
          v.x = (p0 & 0xffffu) | (p1 << 16);
          v.y = (p2 & 0xffffu) | (p3 << 16);
          u16* dst;
          if (A.layer == 0) dst = &A.y0b[((long)tt * 32 + b2) * 4096 + dir * 2048 + j0 + rt * 4];
          else dst = &A.h1a[dir][((long)s * 32 + b2) * 2048 + j0 + rt * 4];
          cstore8(dst, v);
        }
        if (s < 63) {
          int ttn = dir ? 62 - s : s + 1;
          xv4 = *(const ushort4*)(xp + ((((long)ttn * 256 + blockIdx.x) * 32 + batch) * 32)
                                  + (rt * 4 + kg) * 4);
        }
      }
    }
  }
}

// ---------------- H=1024 cell ----------------
__device__ __forceinline__ void stage_w1024(u16* Wl, int m, const u16* W, int j0, int tid) {
  for (int e = tid; e < 2048; e += 512) {
    int kh = e >> 10, s = (e >> 6) & 15, el = e & 63;
    int tr = el & 15;
    long gr = (long)(tr & 3) * 1024 + j0 + (tr >> 2);
    *(uint4*)&Wl[(((m * 2 + kh) * 16 + s) * 64 + el) * 8] =
        *(const uint4*)&W[gr * 1024 + kh * 512 + (el >> 4) * 8 + s * 32];
  }
}

__device__ __forceinline__ void cell1024_lds(
    const u16* Wl, int m0, int m1,
    int j0, int tid, float* red,
    const u16* X0, long x0ld,
    const u16* X1, long x1ld,
    float xg0, float xg1, float xg2, float xg3,
    float b0, float b1, float b2, float b3,
    float co, float* crp,
    u16* hout, long hld, float* houtf, long hfld) {
  const int w = tid >> 6, l = tid & 63;
  const int bh = w & 1, kh = w >> 1;
  const int kg = l >> 4;
  const int koff = kh * 256 + kg * 8;
  const int batch = bh * 16 + (l & 15);
  const int sbase = (kh >> 1) * 16 + (kh & 1) * 8;
  const int jout = j0 + kg;
  f32x4 acc = {0.f, 0.f, 0.f, 0.f};
  if (X0) {
    const u16* xpt = X0 + (long)batch * x0ld + koff;
    const int sb = m0 * 32 + sbase;
    uint4 bv[8]; short8 av[8];
#pragma unroll
    for (int uu = 0; uu < 8; ++uu) bv[uu] = *(const uint4*)(xpt + (long)uu * 32);
#pragma unroll
    for (int uu = 0; uu < 8; ++uu) av[uu] = *(const short8*)&Wl[((sb + uu) * 64 + l) * 8];
#pragma unroll
    for (int uu = 0; uu < 8; ++uu)
      acc = __builtin_amdgcn_mfma_f32_16x16x32_bf16(av[uu], *(short8*)&bv[uu], acc, 0, 0, 0);
  }
  if (X1) {
    const u16* xpt = X1 + (long)batch * x1ld + koff;
    const int sb = m1 * 32 + sbase;
    uint4 bv[8]; short8 av[8];
#pragma unroll
    for (int uu = 0; uu < 8; ++uu) bv[uu] = *(const uint4*)(xpt + (long)uu * 32);
#pragma unroll
    for (int uu = 0; uu < 8; ++uu) av[uu] = *(const short8*)&Wl[((sb + uu) * 64 + l) * 8];
#pragma unroll
    for (int uu = 0; uu < 8; ++uu)
      acc = __builtin_amdgcn_mfma_f32_16x16x32_bf16(av[uu], *(short8*)&bv[uu], acc, 0, 0, 0);
  }
  if (kh) *(f32x4*)&red[((kh - 1) * 2 + bh) * 256 + l * 4] = acc;
  __syncthreads();
  if (kh == 0) {
#pragma unroll
    for (int p = 0; p < 3; ++p) {
      f32x4 o = *(f32x4*)&red[(p * 2 + bh) * 256 + l * 4];
      acc[0] += o[0]; acc[1] += o[1]; acc[2] += o[2]; acc[3] += o[3];
    }
    float g0 = acc[0] + b0 + xg0;
    float g1 = acc[1] + b1 + xg1;
    float g2 = acc[2] + b2 + xg2;
    float g3 = acc[3] + b3 + xg3;
    float iv = sigf(g0), fv = sigf(g1), gv = tanhf(g2), ov = sigf(g3);
    float c = fv * co + iv * gv;
    *crp = c;
    float h = ov * tanhf(c);
    if (houtf) houtf[(long)batch * hfld + jout] = h;
    unsigned hbits = f2bf(h);
    unsigned p0 = __shfl((int)hbits, (l & 15));
    unsigned p1 = __shfl((int)hbits, (l & 15) + 16);
    unsigned p2 = __shfl((int)hbits, (l & 15) + 32);
    unsigned p3 = __shfl((int)hbits, (l & 15) + 48);
    if (l < 16) {
      int b2 = bh * 16 + l;
      uv2 v;
      v.x = (p0 & 0xffffu) | (p1 << 16);
      v.y = (p2 & 0xffffu) | (p3 << 16);
      cstore8(&hout[(long)b2 * hld + j0], v);
    }
  }
}

// ---------------- persistent conductor ----------------
struct CondArgs {
  const u16 *c0h, *c1w, *c1h, *tvecb;
  const float* tvec;
  u16 *yc0b, *embb;
  float* embf;
  const float *b0i, *b0h, *b1i, *b1h;
  unsigned* bar;
};
__global__ __launch_bounds__(512) void cond_coop(CondArgs A) {
  __shared__ u16 Wl[3 * 32 * 512];
  __shared__ __align__(16) float red[6 * 256];
  const int j0 = blockIdx.x * 4;
  const int tid = threadIdx.x;
  const int w = tid >> 6, l = tid & 63;
  const int bh = w & 1;
  const int jout = j0 + (l >> 4);
  const int batch = bh * 16 + (l & 15);
  stage_w1024(Wl, 0, A.c0h, j0, tid);
  stage_w1024(Wl, 1, A.c1w, j0, tid);
  stage_w1024(Wl, 2, A.c1h, j0, tid);
  const float cb00 = A.b0i[jout] + A.b0h[jout];
  const float cb01 = A.b0i[1024 + jout] + A.b0h[1024 + jout];
  const float cb02 = A.b0i[2048 + jout] + A.b0h[2048 + jout];
  const float cb03 = A.b0i[3072 + jout] + A.b0h[3072 + jout];
  const float cb10 = A.b1i[jout] + A.b1h[jout];
  const float cb11 = A.b1i[1024 + jout] + A.b1h[1024 + jout];
  const float cb12 = A.b1i[2048 + jout] + A.b1h[2048 + jout];
  const float cb13 = A.b1i[3072 + jout] + A.b1h[3072 + jout];
  const float c0init = A.tvec[2048 + (long)batch * 4096 + jout];
  const float c1init = A.tvec[3072 + (long)batch * 4096 + jout];
  __syncthreads();
  float cr0 = c0init, cr1 = c1init;
  int bi = 0;
  for (int u = 0; u < NU; ++u) {
    cell1024_lds(Wl, 0, -1, j0, tid, red,
                 u ? A.yc0b + (long)(u - 1) * 32 * 1024 : A.tvecb, u ? 1024 : 4096,
                 nullptr, 0,
                 0.f, 0.f, 0.f, 0.f,
                 cb00, cb01, cb02, cb03,
                 cr0, &cr0,
                 A.yc0b + (long)u * 32 * 1024, 1024, nullptr, 0);
    gbar(A.bar + (long)(bi++) * BSTRIDE);
    cell1024_lds(Wl, 1, 2, j0, tid, red,
                 A.yc0b + (long)u * 32 * 1024, 1024,
                 u ? A.embb + (long)(u - 1) * 32 * 1024 : A.tvecb + 1024, u ? 1024 : 4096,
                 0.f, 0.f, 0.f, 0.f,
                 cb10, cb11, cb12, cb13,
                 cr1, &cr1,
                 A.embb + (long)u * 32 * 1024, 1024, A.embf + (long)u * 32 * 1024, 1024);
    if (u < NU - 1) gbar(A.bar + (long)(bi++) * BSTRIDE);
  }
}

// ---------------- persistent hierarchical decoder ----------------
struct DecArgs {
  const u16 *d1h, *wfuse, *d2w, *d2h, *xeb, *sallb;
  const float* sall;
  u16 *dh1all, *dh2all;
  const float *bfuse, *b1h, *b2i, *b2h;
  unsigned* bar;
};
__global__ __launch_bounds__(512) void dec_coop(DecArgs A) {
  __shared__ u16 Wl[4 * 32 * 512];
  __shared__ __align__(16) float red[6 * 256];
  const int j0 = blockIdx.x * 4;
  const int tid = threadIdx.x;
  const int w = tid >> 6, l = tid & 63;
  const int bh = w & 1;
  const int kg = l >> 4;
  const int jout = j0 + kg;
  const int batch = bh * 16 + (l & 15);
  stage_w1024(Wl, 0, A.d1h, j0, tid);
  stage_w1024(Wl, 1, A.wfuse, j0, tid);
  stage_w1024(Wl, 2, A.d2w, j0, tid);
  stage_w1024(Wl, 3, A.d2h, j0, tid);
  const float b1z0 = A.b1h[jout], b1z1 = A.b1h[1024 + jout],
              b1z2 = A.b1h[2048 + jout], b1z3 = A.b1h[3072 + jout];
  const float b1n0 = b1z0 + A.bfuse[jout], b1n1 = b1z1 + A.bfuse[1024 + jout],
              b1n2 = b1z2 + A.bfuse[2048 + jout], b1n3 = b1z3 + A.bfuse[3072 + jout];
  const float b20 = A.b2i[jout] + A.b2h[jout];
  const float b21 = A.b2i[1024 + jout] + A.b2h[1024 + jout];
  const float b22 = A.b2i[2048 + jout] + A.b2h[2048 + jout];
  const float b23 = A.b2i[3072 + jout] + A.b2h[3072 + jout];
  const u16* xqb = A.xeb + (long)blockIdx.x * 128 * 16;
  ushort4 xq4 = *(const ushort4*)(xqb + (long)batch * 16 + kg * 4);
  float con1 = A.sall[(long)batch * 4096 + 2048 + jout];
  float con2 = A.sall[(long)batch * 4096 + 3072 + jout];
  __syncthreads();
  float cr1 = 0.f, cr2 = 0.f;
  int bi = 0;
  for (int t = 0; t < TT; ++t) {
    const int u = t >> 4, sg = t & 15;
    if (sg == 0) { cr1 = con1; cr2 = con2; }
    cell1024_lds(Wl, 0, 1, j0, tid, red,
                 sg ? A.dh1all + (long)(t - 1) * 32 * 1024 : A.sallb + (long)u * 32 * 4096,
                 sg ? 1024 : 4096,
                 t ? A.dh2all + (long)(t - 1) * 32 * 1024 : nullptr, 1024,
                 bf2f(xq4.x), bf2f(xq4.y), bf2f(xq4.z), bf2f(xq4.w),
                 t ? b1n0 : b1z0, t ? b1n1 : b1z1, t ? b1n2 : b1z2, t ? b1n3 : b1z3,
                 cr1, &cr1,
                 A.dh1all + (long)t * 32 * 1024, 1024, nullptr, 0);
    gbar(A.bar + (long)(bi++) * BSTRIDE);
    cell1024_lds(Wl, 2, 3, j0, tid, red,
                 A.dh1all + (long)t * 32 * 1024, 1024,
                 sg ? A.dh2all + (long)(t - 1) * 32 * 1024 : A.sallb + (long)u * 32 * 4096 + 1024,
                 sg ? 1024 : 4096,
                 0.f, 0.f, 0.f, 0.f,
                 b20, b21, b22, b23,
                 cr2, &cr2,
                 A.dh2all + (long)t * 32 * 1024, 1024, nullptr, 0);
    if (sg == 15 && u < 3) {
      xq4 = *(const ushort4*)(xqb + (long)(u + 1) * 32 * 16 + (long)batch * 16 + kg * 4);
      con1 = A.sall[(long)(u + 1) * 32 * 4096 + (long)batch * 4096 + 2048 + jout];
      con2 = A.sall[(long)(u + 1) * 32 * 4096 + (long)batch * 4096 + 3072 + jout];
    }
    if (t < TT - 1) gbar(A.bar + (long)(bi++) * BSTRIDE);
  }
}

// ---------------- final p = dh2all @ w4^T + b4 -> out ----------------
__global__ __launch_bounds__(256) void proj_all(const u16* __restrict__ dh2all,
                                                const u16* __restrict__ w4b,
                                                const float* __restrict__ b4,
                                                float* __restrict__ out) {
  __shared__ u16 hs[8 * 1024];
  const int r0 = blockIdx.x * 8;
  for (int e = threadIdx.x; e < 1024; e += 256)
    ((uint4*)hs)[e] = ((const uint4*)(dh2all + (long)r0 * 1024))[e];
  __syncthreads();
  for (int o = threadIdx.x; o < 8 * INPW; o += 256) {
    int rr = o / INPW, n = o % INPW;
    const u16* wr = w4b + (long)n * 1024;
    const u16* hr = hs + rr * 1024;
    float s = 0.0f;
    for (int k = 0; k < 1024; ++k) s += bf2f(hr[k]) * bf2f(wr[k]);
    int row = r0 + rr;
    int tt = row >> 5, b = row & 31;
    out[((long)b * TT + tt) * INPW + n] = s + b4[n];
  }
}

// =====================================================================
extern "C" void kernel_launch(void* const* d_in, const int* in_sizes, int n_in,
                              void* d_out, int out_size, void* d_ws, size_t ws_size,
                              hipStream_t stream) {
  (void)in_sizes; (void)n_in; (void)out_size;
  const float* x        = (const float*)d_in[0];
  const float* eps      = (const float*)d_in[1];
  const float* e0f_wih  = (const float*)d_in[2];
  const float* e0f_whh  = (const float*)d_in[3];
  const float* e0f_bih  = (const float*)d_in[4];
  const float* e0f_bhh  = (const float*)d_in[5];
  const float* e0b_wih  = (const float*)d_in[6];
  const float* e0b_whh  = (const float*)d_in[7];
  const float* e0b_bih  = (const float*)d_in[8];
  const float* e0b_bhh  = (const float*)d_in[9];
  const float* e1f_wih  = (const float*)d_in[10];
  const float* e1f_whh  = (const float*)d_in[11];
  const float* e1f_bih  = (const float*)d_in[12];
  const float* e1f_bhh  = (const float*)d_in[13];
  const float* e1b_wih  = (const float*)d_in[14];
  const float* e1b_whh  = (const float*)d_in[15];
  const float* e1b_bih  = (const float*)d_in[16];
  const float* e1b_bhh  = (const float*)d_in[17];
  const float* wm  = (const float*)d_in[18];
  const float* bm  = (const float*)d_in[19];
  const float* wsw = (const float*)d_in[20];
  const float* bsv = (const float*)d_in[21];
  const float* w2  = (const float*)d_in[22];
  const float* b2  = (const float*)d_in[23];
  const float* c0_whh = (const float*)d_in[25];
  const float* c0_bih = (const float*)d_in[26];
  const float* c0_bhh = (const float*)d_in[27];
  const float* c1_wih = (const float*)d_in[28];
  const float* c1_whh = (const float*)d_in[29];
  const float* c1_bih = (const float*)d_in[30];
  const float* c1_bhh = (const float*)d_in[31];
  const float* w3 = (const float*)d_in[32];
  const float* b3 = (const float*)d_in[33];
  const float* d1_wih = (const float*)d_in[34];
  const float* d1_whh = (const float*)d_in[35];
  const float* d1_bih = (const float*)d_in[36];
  const float* d1_bhh = (const float*)d_in[37];
  const float* d2_wih = (const float*)d_in[38];
  const float* d2_whh = (const float*)d_in[39];
  const float* d2_bih = (const float*)d_in[40];
  const float* d2_bhh = (const float*)d_in[41];
  const float* w4 = (const float*)d_in[42];
  const float* b4 = (const float*)d_in[43];

  float* out = (float*)d_out;
  float* zm_out = out + (size_t)BB * TT * INPW;
  float* zs_out = zm_out + BB * NZ;

  char* wbase = (char*)d_ws;
  size_t cur = 0;
  auto AL = [&](size_t bytes) -> void* {
    void* p = wbase + cur;
    cur = (cur + bytes + 255) & ~(size_t)255;
    return p;
  };
  u16* xb    = (u16*)AL(2048L * 128 * 2);
  u16* e0wf  = (u16*)AL(8192L * 128 * 2);
  u16* e0wb  = (u16*)AL(8192L * 128 * 2);
  u16* e0hf  = (u16*)AL(8192L * 2048 * 2);
  u16* e0hb  = (u16*)AL(8192L * 2048 * 2);
  u16* e1wf  = (u16*)AL(8192L * 4096 * 2);
  u16* e1wb  = (u16*)AL(8192L * 4096 * 2);
  u16* e1hf  = (u16*)AL(8192L * 2048 * 2);
  u16* e1hb  = (u16*)AL(8192L * 2048 * 2);
  u16* c0h   = (u16*)AL(4096L * 1024 * 2);
  u16* c1w   = (u16*)AL(4096L * 1024 * 2);
  u16* c1h   = (u16*)AL(4096L * 1024 * 2);
  u16* d1we  = (u16*)AL(4096L * 1024 * 2);
  u16* d1wp  = (u16*)AL(4096L * 128 * 2);
  u16* d1h   = (u16*)AL(4096L * 1024 * 2);
  u16* d2w   = (u16*)AL(4096L * 1024 * 2);
  u16* d2h   = (u16*)AL(4096L * 1024 * 2);
  u16* w4b   = (u16*)AL(90L * 1024 * 2);
  u16* w4tb  = (u16*)AL(1024L * 128 * 2);
  u16* wfuse = (u16*)AL(4096L * 1024 * 2);
  float* bfuse = (float*)AL(4096L * 4);
  float* pb_e0f = (float*)AL(8192L * 4);
  float* pb_e0b = (float*)AL(8192L * 4);
  float* pb_e1f = (float*)AL(8192L * 4);
  float* pb_e1b = (float*)AL(8192L * 4);
  float* pb_d1  = (float*)AL(4096L * 4);
  u16* xp0f  = (u16*)AL(2048L * 8192 * 2);
  u16* xp0b  = (u16*)AL(2048L * 8192 * 2);
  u16* y0b   = (u16*)AL(2048L * 4096 * 2);
  u16* xp1f  = (u16*)AL(2048L * 8192 * 2);
  u16* xp1b  = (u16*)AL(2048L * 8192 * 2);
  u16* h1af  = (u16*)AL(64L * 32 * 2048 * 2);
  u16* h1ab  = (u16*)AL(64L * 32 * 2048 * 2);
  u16* tvecb = (u16*)AL(32L * 4096 * 2);
  u16* yc0b  = (u16*)AL(4L * 32 * 1024 * 2);
  u16* embb  = (u16*)AL(4L * 32 * 1024 * 2);
  u16* sallb = (u16*)AL(128L * 4096 * 2);
  u16* xeb   = (u16*)AL(128L * 4096 * 2);
  u16* dh1all= (u16*)AL(64L * 32 * 1024 * 2);
  u16* dh2all= (u16*)AL(64L * 32 * 1024 * 2);
  float* htb  = (float*)AL(32L * 4096 * 4);
  float* zbuf = (float*)AL(32L * 512 * 4);
  float* tvec = (float*)AL(32L * 4096 * 4);
  float* embf = (float*)AL(128L * 1024 * 4);
  float* sall = (float*)AL(128L * 4096 * 4);
  unsigned* barp = (unsigned*)AL(400L * BSTRIDE * 4);
  if (cur > ws_size) return;

  unsigned* bar_enc0 = barp;
  unsigned* bar_enc1 = barp + 128L * BSTRIDE;
  unsigned* bar_cond = barp + 256L * BSTRIDE;
  unsigned* bar_dec  = barp + 264L * BSTRIDE;

  // ---- conversions (fused) ----
  {
    CvtJobs J{};
    int c = 0;
    auto add = [&](const float* s, u16* d, long n) { J.s[c] = s; J.d[c] = d; J.n[c] = n; ++c; };
    add(e0f_whh, e0hf, 8192L * 2048);
    add(e0b_whh, e0hb, 8192L * 2048);
    add(e1f_whh, e1hf, 8192L * 2048);
    add(e1b_whh, e1hb, 8192L * 2048);
    add(c0_whh, c0h, 4096L * 1024);
    add(c1_wih, c1w, 4096L * 1024);
    add(c1_whh, c1h, 4096L * 1024);
    add(d1_whh, d1h, 4096L * 1024);
    add(d2_wih, d2w, 4096L * 1024);
    add(d2_whh, d2h, 4096L * 1024);
    add(w4, w4b, 90L * 1024);
    J.cnt = c;
    cvt_multi<<<dim3(2048), 256, 0, stream>>>(J);
  }
  cvt_permrow<<<dim3(1, 8192), 128, 0, stream>>>(e0f_wih, 90, 90, e0wf, 128, 2048);
  cvt_permrow<<<dim3(1, 8192), 128, 0, stream>>>(e0b_wih, 90, 90, e0wb, 128, 2048);
  cvt_permrow<<<dim3(16, 8192), 256, 0, stream>>>(e1f_wih, 4096, 4096, e1wf, 4096, 2048);
  cvt_permrow<<<dim3(16, 8192), 256, 0, stream>>>(e1b_wih, 4096, 4096, e1wb, 4096, 2048);
  cvt_permrow<<<dim3(4, 4096), 256, 0, stream>>>(d1_wih, 1114, 1024, d1we, 1024, 1024);
  {
    BPJobs J{};
    J.s[0] = e0f_bih; J.d[0] = pb_e0f; J.H[0] = 2048;
    J.s[1] = e0b_bih; J.d[1] = pb_e0b; J.H[1] = 2048;
    J.s[2] = e1f_bih; J.d[2] = pb_e1f; J.H[2] = 2048;
    J.s[3] = e1b_bih; J.d[3] = pb_e1b; J.H[3] = 2048;
    J.s[4] = d1_bih;  J.d[4] = pb_d1;  J.H[4] = 1024;
    J.cnt = 5;
    bias_perm5<<<dim3(32), 256, 0, stream>>>(J);
  }
  cvt_pad<<<dim3(1, 4096), 128, 0, stream>>>(d1_wih + 1024, 1114, 90, d1wp, 128, 4096);
  xcvt<<<dim3(2048), 128, 0, stream>>>(x, xb);
  w4t_k<<<dim3(1024), 128, 0, stream>>>(w4, w4tb);
  bfuse_k<<<dim3(16), 256, 0, stream>>>(d1_wih, b4, bfuse);
  hipMemsetAsync(barp, 0, 400L * BSTRIDE * 4, stream);

  gemm_bf<<<dim3(256), 256, 0, stream>>>(d1wp, 128, w4tb, 128, nullptr, wfuse, 1024, 128, 0, 32, 8);
  gemm_bf<<<dim3(1024), 256, 0, stream>>>(xb, 128, e0wf, 128, pb_e0f, xp0f, 8192, 128, 1, 16, 64);
  gemm_bf<<<dim3(1024), 256, 0, stream>>>(xb, 128, e0wb, 128, pb_e0b, xp0b, 8192, 128, 1, 16, 64);

  // ---- encoder layer 0 ----
  {
    EncArgs ea{};
    ea.whh[0] = e0hf; ea.whh[1] = e0hb;
    ea.xp[0] = xp0f; ea.xp[1] = xp0b;
    ea.bhh[0] = e0f_bhh; ea.bhh[1] = e0b_bhh;
    ea.y0b = y0b; ea.h1a[0] = h1af; ea.h1a[1] = h1ab; ea.htb = htb;
    ea.bar = bar_enc0; ea.layer = 0;
    void* args[] = {&ea};
    (void)hipLaunchCooperativeKernel((void*)enc_coop, dim3(256), dim3(512), args, 0, stream);
  }

  gemm_bf<<<dim3(1024), 256, 0, stream>>>(y0b, 4096, e1wf, 4096, pb_e1f, xp1f, 8192, 4096, 1, 16, 64);
  gemm_bf<<<dim3(1024), 256, 0, stream>>>(y0b, 4096, e1wb, 4096, pb_e1b, xp1b, 8192, 4096, 1, 16, 64);

  // ---- encoder layer 1 ----
  {
    EncArgs ea{};
    ea.whh[0] = e1hf; ea.whh[1] = e1hb;
    ea.xp[0] = xp1f; ea.xp[1] = xp1b;
    ea.bhh[0] = e1f_bhh; ea.bhh[1] = e1b_bhh;
    ea.y0b = y0b; ea.h1a[0] = h1af; ea.h1a[1] = h1ab; ea.htb = htb;
    ea.bar = bar_enc1; ea.layer = 1;
    void* args[] = {&ea};
    (void)hipLaunchCooperativeKernel((void*)enc_coop, dim3(256), dim3(512), args, 0, stream);
  }

  // ---- latent ----
  latgemm<<<dim3(32), 256, 0, stream>>>(htb, wm, bm, zm_out, 0);
  latgemm<<<dim3(32), 256, 0, stream>>>(htb, wsw, bsv, zs_out, 2);
  zcalc_kernel<<<dim3(64), 256, 0, stream>>>(zm_out, zs_out, eps, zbuf);
  gemm128<<<dim3(1, 32), 256, 0, stream>>>(zbuf, 512, w2, 512, b2, tvec, 4096, 32, 512, 1, tvecb);

  // ---- conductor ----
  {
    CondArgs ca{};
    ca.c0h = c0h; ca.c1w = c1w; ca.c1h = c1h;
    ca.tvecb = tvecb; ca.tvec = tvec;
    ca.yc0b = yc0b; ca.embb = embb; ca.embf = embf;
    ca.b0i = c0_bih; ca.b0h = c0_bhh; ca.b1i = c1_bih; ca.b1h = c1_bhh;
    ca.bar = bar_cond;
    void* args[] = {&ca};
    (void)hipLaunchCooperativeKernel((void*)cond_coop, dim3(256), dim3(512), args, 0, stream);
  }

  // ---- decoder prep ----
  gemm128<<<dim3(1, 32), 256, 0, stream>>>(embf, 1024, w3, 1024, b3, sall, 4096, 128, 1024, 1, sallb);
  gemm_bf<<<dim3(32), 256, 0, stream>>>(embb, 1024, d1we, 1024, pb_d1, xeb, 4096, 1024, 2, 1, 32);

  // ---- hierarchical decoder ----
  {
    DecArgs da{};
    da.d1h = d1h; da.wfuse = wfuse; da.d2w = d2w; da.d2h = d2h;
    da.xeb = xeb; da.sallb = sallb; da.sall = sall;
    da.dh1all = dh1all; da.dh2all = dh2all;
    da.bfuse = bfuse; da.b1h = d1_bhh; da.b2i = d2_bih; da.b2h = d2_bhh;
    da.bar = bar_dec;
    void* args[] = {&da};
    (void)hipLaunchCooperativeKernel((void*)dec_coop, dim3(256), dim3(512), args, 0, stream);
  }

  // ---- outputs ----
  proj_all<<<dim3(256), 256, 0, stream>>>(dh2all, w4b, b4, out);
  softmax_kernel<<<dim3(BB * TT), 64, 0, stream>>>(out);
}

// Round 15
// 4856.907 us; speedup vs baseline: 1.0122x; 1.0122x over previous
//
#include <hip/hip_runtime.h>
#include <hip/hip_cooperative_groups.h>
#include <math.h>

#define BB 32
#define TT 64
#define INPW 90
#define NU 4
#define NH1 2048
#define NHC 1024
#define NHD 1024
#define NZ 512
// barrier slot: 16 sub-counters @ 2KB stride, master @ 16*2KB, 8 release flags @ (17+k)*2KB
#define BSTRIDE 12800  // u32 per slot (25 * 512)

typedef unsigned short u16;
typedef __attribute__((ext_vector_type(8))) short short8;
typedef __attribute__((ext_vector_type(4))) float f32x4;
typedef __attribute__((ext_vector_type(4))) unsigned uv4;
typedef __attribute__((ext_vector_type(2))) unsigned uv2;

__device__ __forceinline__ float sigf(float v) { return 1.0f / (1.0f + __expf(-v)); }

__device__ __forceinline__ u16 f2bf(float f) {
  unsigned u = __float_as_uint(f);
  unsigned r = (u + 0x7FFFu + ((u >> 16) & 1u)) >> 16;
  return (u16)r;
}
__device__ __forceinline__ float bf2f(u16 b) { return __uint_as_float(((unsigned)b) << 16); }

// ---- coherence helpers (cross-XCD, no cache flush) ----
__device__ __forceinline__ void cstore16(u16* p, uv4 v) {
  asm volatile("global_store_dwordx4 %0, %1, off sc0 sc1" :: "v"(p), "v"(v) : "memory");
}
__device__ __forceinline__ void cstore8(u16* p, uv2 v) {
  asm volatile("global_store_dwordx2 %0, %1, off sc0 sc1" :: "v"(p), "v"(v) : "memory");
}
__device__ __forceinline__ void cstore4(unsigned* p, unsigned v) {
  asm volatile("global_store_dword %0, %1, off sc0 sc1" :: "v"(p), "v"(v) : "memory");
}
__device__ __forceinline__ unsigned fload(const unsigned* p) {
  unsigned r;
  asm volatile("global_load_dword %0, %1, off sc0 sc1\n\ts_waitcnt vmcnt(0)"
               : "=v"(r) : "v"(p) : "memory");
  return r;
}
// channel-spread two-level barrier, one-shot per slot; 256 blocks.
__device__ __forceinline__ void gbar(unsigned* base) {
  asm volatile("s_waitcnt vmcnt(0)" ::: "memory");
  __syncthreads();
  if (threadIdx.x == 0) {
    unsigned old = atomicAdd(&base[(blockIdx.x & 15) * 512], 1u);
    if (old == 15u) {
      unsigned m = atomicAdd(&base[16 * 512], 1u);
      if (m == 15u) {
#pragma unroll
        for (int k = 0; k < 8; ++k) cstore4(&base[(17 + k) * 512], 1u);
        asm volatile("s_waitcnt vmcnt(0)" ::: "memory");
      }
    }
    while (!fload(&base[(17 + (blockIdx.x & 7)) * 512])) __builtin_amdgcn_s_sleep(2);
  }
  __syncthreads();
}

// async global->LDS, 16B per lane
__device__ __forceinline__ void gload16(const u16* g, u16* l) {
  __builtin_amdgcn_global_load_lds(
      (const __attribute__((address_space(1))) unsigned*)g,
      (__attribute__((address_space(3))) unsigned*)l, 16, 0, 0);
}

// ---------------- conversion kernels ----------------
struct CvtJobs { const float* s[12]; u16* d[12]; long n[12]; int cnt; };
__global__ void cvt_multi(CvtJobs J) {
  long stride = (long)gridDim.x * 256 * 4;
  for (int j = 0; j < J.cnt; ++j) {
    const float* s = J.s[j]; u16* d = J.d[j]; long n = J.n[j];
    for (long i = ((long)blockIdx.x * 256 + threadIdx.x) * 4; i < n; i += stride) {
      float4 v = *(const float4*)&s[i];
      d[i] = f2bf(v.x); d[i + 1] = f2bf(v.y); d[i + 2] = f2bf(v.z); d[i + 3] = f2bf(v.w);
    }
  }
}

struct BPJobs { const float* s[5]; float* d[5]; int H[5]; int cnt; };
__global__ void bias_perm5(BPJobs J) {
  for (int j = 0; j < J.cnt; ++j) {
    int tot = 4 * J.H[j];
    for (int n = blockIdx.x * 256 + threadIdx.x; n < tot; n += gridDim.x * 256)
      J.d[j][n] = J.s[j][(long)(n & 3) * J.H[j] + (n >> 2)];
  }
}

__global__ void cvt_pad(const float* __restrict__ s, int sld, int cols,
                        u16* __restrict__ d, int dld, int rows) {
  int c = blockIdx.x * blockDim.x + threadIdx.x;
  int r = blockIdx.y;
  if (c >= dld) return;
  d[(long)r * dld + c] = (c < cols) ? f2bf(s[(long)r * sld + c]) : (u16)0;
}

// gate-interleaved row permutation: dst row r <- src row (r&3)*H + (r>>2)
__global__ void cvt_permrow(const float* __restrict__ s, int sld, int cols,
                            u16* __restrict__ d, int dld, int H) {
  int c = blockIdx.x * blockDim.x + threadIdx.x;
  int r = blockIdx.y;
  if (c >= dld) return;
  long sr = (long)(r & 3) * H + (r >> 2);
  d[(long)r * dld + c] = (c < cols) ? f2bf(s[sr * sld + c]) : (u16)0;
}

__global__ void xcvt(const float* __restrict__ x, u16* __restrict__ xb) {
  int r = blockIdx.x, c = threadIdx.x;
  int b = r & 31, t = r >> 5;
  float v = (c < INPW) ? x[((long)b * TT + t) * INPW + c] : 0.0f;
  xb[(long)r * 128 + c] = f2bf(v);
}

__global__ void w4t_k(const float* __restrict__ w4, u16* __restrict__ w4tb) {
  int k = blockIdx.x, n = threadIdx.x;
  w4tb[(long)k * 128 + n] = (n < INPW) ? f2bf(w4[(long)n * NHD + k]) : (u16)0;
}

__global__ void bfuse_k(const float* __restrict__ d1_wih, const float* __restrict__ b4,
                        float* __restrict__ bfuse) {
  int r = blockIdx.x * 256 + threadIdx.x;
  if (r >= 4096) return;
  float s = 0.0f;
  for (int n = 0; n < INPW; ++n) s += d1_wih[(long)r * 1114 + 1024 + n] * b4[n];
  bfuse[r] = s;
}

// ---------------- bf16 MFMA GEMM: global_load_lds dbuf, XCD-aware 1D grid ----------------
// mode 0: C[m*ldc+n]
// mode 1 (enc xp): dst = (((m>>5)*256+(n>>5))*32+(m&31))*32 + (n&31)
// mode 2 (dec xeb): dst = ((n>>4)*128+m)*16 + (n&15)
__global__ __launch_bounds__(256) void gemm_bf(
    const u16* __restrict__ A, int lda, const u16* __restrict__ Bw, int ldb,
    const float* __restrict__ bias, u16* __restrict__ C, int ldc, int K, int mode,
    int nbm, int nbn) {
  __shared__ u16 Asm[2][128 * 64];
  __shared__ u16 Bsm[2][128 * 64];
  const int tid = threadIdx.x;
  const int w = tid >> 6, l = tid & 63, q = (tid >> 4) & 3, ln = tid & 15;
  const int wm = w & 1, wn = w >> 1;
  int fid = blockIdx.x;
  int sidx = fid >> 3, xcd = fid & 7;
  int bm, bn;
  if ((nbm & 7) == 0) { bn = sidx % nbn; bm = xcd * (nbm >> 3) + sidx / nbn; }
  else if ((nbn & 7) == 0) { bm = sidx % nbm; bn = xcd * (nbn >> 3) + sidx / nbm; }
  else { bm = fid % nbm; bn = fid / nbm; }
  const long am0 = (long)bm * 128;
  const long bn0 = (long)bn * 128;
  const u16* Ap0 = A + am0 * lda;
  const u16* Bp0 = Bw + bn0 * ldb;
  f32x4 acc[4][4] = {};

  auto stage = [&](int b, int k0) {
#pragma unroll
    for (int i = 0; i < 4; ++i) {
      int row = (w * 4 + i) * 8 + (l >> 3);
      int col = (((l & 7) ^ (row & 7)) << 3) + k0;
      gload16(Ap0 + (long)row * lda + col, &Asm[b][(w * 4 + i) * 512]);
      gload16(Bp0 + (long)row * ldb + col, &Bsm[b][(w * 4 + i) * 512]);
    }
  };

  const int kt = K >> 6;
  stage(0, 0);
  asm volatile("s_waitcnt vmcnt(0)" ::: "memory");
  __syncthreads();
  int buf = 0;
  for (int t = 0; t < kt; ++t) {
    if (t + 1 < kt) stage(buf ^ 1, (t + 1) << 6);
#pragma unroll
    for (int kh = 0; kh < 2; ++kh) {
      short8 af[4], bg[4];
#pragma unroll
      for (int tt2 = 0; tt2 < 4; ++tt2) {
        int arr = wm * 64 + tt2 * 16 + ln;
        af[tt2] = *(short8*)&Asm[buf][arr * 64 + (((q + 4 * kh) ^ (arr & 7)) << 3)];
        int brr = wn * 64 + tt2 * 16 + ln;
        bg[tt2] = *(short8*)&Bsm[buf][brr * 64 + (((q + 4 * kh) ^ (brr & 7)) << 3)];
      }
#pragma unroll
      for (int mt = 0; mt < 4; ++mt)
#pragma unroll
        for (int nt = 0; nt < 4; ++nt)
          acc[mt][nt] = __builtin_amdgcn_mfma_f32_16x16x32_bf16(af[mt], bg[nt], acc[mt][nt], 0, 0, 0);
    }
    asm volatile("s_waitcnt vmcnt(0)" ::: "memory");
    __syncthreads();
    buf ^= 1;
  }
#pragma unroll
  for (int nt = 0; nt < 4; ++nt) {
    long n = bn0 + wn * 64 + nt * 16 + ln;
    float bv = bias ? bias[n] : 0.0f;
#pragma unroll
    for (int mt = 0; mt < 4; ++mt) {
#pragma unroll
      for (int r = 0; r < 4; ++r) {
        long m = am0 + wm * 64 + mt * 16 + (q << 2) + r;
        long dst;
        if (mode == 0) {
          dst = m * ldc + n;
        } else if (mode == 1) {
          dst = (((m >> 5) * 256 + (n >> 5)) * 32 + (m & 31)) * 32 + (n & 31);
        } else {
          dst = ((n >> 4) * 128 + m) * 16 + (n & 15);
        }
        C[dst] = f2bf(acc[mt][nt][r] + bv);
      }
    }
  }
}

// ---------------- fp32 GEMM (tvec / sall) ----------------
__global__ __launch_bounds__(256) void gemm128(
    const float* __restrict__ A, int lda, const float* __restrict__ W, int ldw,
    const float* __restrict__ bias, float* __restrict__ C, int ldc,
    int M, int K, int act, u16* __restrict__ Cb) {
  __shared__ float As[16][132];
  __shared__ float Bs[16][132];
  const int tid = threadIdx.x;
  const int bm = blockIdx.x, bn = blockIdx.y;
  const int tm = tid & 15, tn = tid >> 4;
  float acc[8][8] = {};
  for (int k0 = 0; k0 < K; k0 += 16) {
#pragma unroll
    for (int it = 0; it < 2; ++it) {
      int e = it * 256 + tid;
      int r = e >> 2, c4 = (e & 3) * 4;
      int m = bm * 128 + r;
      float4 v = make_float4(0.f, 0.f, 0.f, 0.f);
      if (m < M) v = *(const float4*)&A[(long)m * lda + k0 + c4];
      As[c4 + 0][r] = v.x; As[c4 + 1][r] = v.y; As[c4 + 2][r] = v.z; As[c4 + 3][r] = v.w;
      int n = bn * 128 + r;
      float4 w = *(const float4*)&W[(long)n * ldw + k0 + c4];
      Bs[c4 + 0][r] = w.x; Bs[c4 + 1][r] = w.y; Bs[c4 + 2][r] = w.z; Bs[c4 + 3][r] = w.w;
    }
    __syncthreads();
#pragma unroll
    for (int kk = 0; kk < 16; ++kk) {
      float4 a0 = *(const float4*)&As[kk][tm * 8];
      float4 a1 = *(const float4*)&As[kk][tm * 8 + 4];
      float4 b0 = *(const float4*)&Bs[kk][tn * 8];
      float4 b1 = *(const float4*)&Bs[kk][tn * 8 + 4];
      float av[8] = {a0.x, a0.y, a0.z, a0.w, a1.x, a1.y, a1.z, a1.w};
      float bv[8] = {b0.x, b0.y, b0.z, b0.w, b1.x, b1.y, b1.z, b1.w};
#pragma unroll
      for (int i = 0; i < 8; ++i)
#pragma unroll
        for (int j = 0; j < 8; ++j)
          acc[i][j] += av[i] * bv[j];
    }
    __syncthreads();
  }
#pragma unroll
  for (int i = 0; i < 8; ++i) {
    int m = bm * 128 + tm * 8 + i;
    if (m >= M) continue;
#pragma unroll
    for (int j = 0; j < 8; ++j) {
      int n = bn * 128 + tn * 8 + j;
      float v = acc[i][j] + bias[n];
      if (act == 1) v = tanhf(v);
      else if (act == 2) v = log1pf(__expf(v));
      C[(long)m * ldc + n] = v;
      if (Cb) Cb[(long)m * ldc + n] = f2bf(v);
    }
  }
}

// ---------------- latent head ----------------
__global__ __launch_bounds__(256) void latgemm(
    const float* __restrict__ A, const float* __restrict__ W,
    const float* __restrict__ bias, float* __restrict__ C, int act) {
  __shared__ float red[16][16][32];
  const int tid = threadIdx.x;
  const int c = tid & 15, ksl = tid >> 4;
  const int n = blockIdx.x * 16 + c;
  const float* wp = W + (long)n * 4096 + ksl * 256;
  const float* ap = A + ksl * 256;
  float acc[32];
#pragma unroll
  for (int r = 0; r < 32; ++r) acc[r] = 0.f;
  for (int k = 0; k < 256; k += 4) {
    float4 wv = *(const float4*)(wp + k);
#pragma unroll
    for (int r = 0; r < 32; ++r) {
      float4 hv = *(const float4*)(ap + (long)r * 4096 + k);
      acc[r] += hv.x * wv.x + hv.y * wv.y + hv.z * wv.z + hv.w * wv.w;
    }
  }
#pragma unroll
  for (int r = 0; r < 32; ++r) red[ksl][c][r] = acc[r];
  __syncthreads();
  for (int o = tid; o < 512; o += 256) {
    int cc = o >> 5, r = o & 31;
    float s = 0.f;
#pragma unroll
    for (int p = 0; p < 16; ++p) s += red[p][cc][r];
    s += bias[blockIdx.x * 16 + cc];
    if (act == 2) s = log1pf(__expf(s));
    C[(long)r * 512 + blockIdx.x * 16 + cc] = s;
  }
}

__global__ void zcalc_kernel(const float* __restrict__ zm, const float* __restrict__ zs,
                             const float* __restrict__ eps, float* __restrict__ z) {
  int e = blockIdx.x * 256 + threadIdx.x;
  if (e < BB * NZ) z[e] = zm[e] + eps[e] * zs[e];
}

__global__ void softmax_kernel(float* __restrict__ out) {
  long row = blockIdx.x;
  float* p = out + row * INPW;
  int lane = threadIdx.x;
  float v0 = (lane < INPW) ? p[lane] : -1e30f;
  float v1 = (lane + 64 < INPW) ? p[lane + 64] : -1e30f;
  float m = fmaxf(v0, v1);
#pragma unroll
  for (int off = 32; off > 0; off >>= 1) m = fmaxf(m, __shfl_xor(m, off));
  float e0 = (lane < INPW) ? __expf(v0 - m) : 0.0f;
  float e1 = (lane + 64 < INPW) ? __expf(v1 - m) : 0.0f;
  float sum = e0 + e1;
#pragma unroll
  for (int off = 32; off > 0; off >>= 1) sum += __shfl_xor(sum, off);
  float inv = 1.0f / sum;
  if (lane < INPW) p[lane] = e0 * inv;
  if (lane + 64 < INPW) p[lane + 64] = e1 * inv;
}

// ---------------- persistent encoder (round-13 structure) ----------------
struct EncArgs {
  const u16* whh[2];
  const u16* xp[2];
  const float* bhh[2];
  u16* y0b;
  u16* h1a[2];
  float* htb;
  unsigned* bar;
  int layer;
};

__global__ __launch_bounds__(512) void enc_coop(EncArgs A) {
  __shared__ u16 Wl[2 * 64 * 64 * 8];
  __shared__ __align__(16) float red[4 * 64 * 4];
  __shared__ __align__(16) u16 hstage[32][8];
  const int tid = threadIdx.x;
  const int w = tid >> 6, l = tid & 63;
  const int rt = w & 1, bh = (w >> 1) & 1, kh = w >> 2;
  const int kg = l >> 4, b0 = l & 15;
  const int j0 = blockIdx.x * 8;
  const int jout = j0 + rt * 4 + kg;
  const int batch = bh * 16 + b0;
  float* redp = &red[((bh * 2 + rt) * 64 + l) * 4];

  for (int dir = 0; dir < 2; ++dir) {
    __syncthreads();
    {
      const u16* W = A.whh[dir];
      for (int e = tid; e < 8192; e += 512) {
        int ert = e >> 12, es = (e >> 6) & 63, el = e & 63;
        int etr = el & 15;
        long gr = (long)(etr & 3) * 2048 + j0 + ert * 4 + (etr >> 2);
        *(uint4*)&Wl[((ert * 64 + es) * 64 + el) * 8] =
            *(const uint4*)&W[gr * 2048 + (el >> 4) * 8 + (long)es * 32];
      }
    }
    __syncthreads();
    const float* bhh = A.bhh[dir];
    const u16* xp = A.xp[dir];
    const float bi0 = bhh[jout], bi1 = bhh[2048 + jout],
                bi2 = bhh[4096 + jout], bi3 = bhh[6144 + jout];
    float creg = 0.f;
    ushort4 xv4 = make_ushort4(0, 0, 0, 0);
    if (kh == 0) {
      int tt0 = dir ? 63 : 0;
      xv4 = *(const ushort4*)(xp + ((((long)tt0 * 256 + blockIdx.x) * 32 + batch) * 32)
                              + (rt * 4 + kg) * 4);
    }
    for (int s = 0; s < 64; ++s) {
      if (s) gbar(A.bar + (long)(dir * 63 + (s - 1)) * BSTRIDE);
      const int tt = dir ? 63 - s : s;
      f32x4 acc = {0.f, 0.f, 0.f, 0.f};
      if (s) {
        const u16* hb; long hld;
        if (A.layer == 0) {
          int tp = dir ? tt + 1 : tt - 1;
          hb = A.y0b + (long)tp * 32 * 4096 + dir * 2048;
          hld = 4096;
        } else {
          hb = A.h1a[dir] + (long)(s - 1) * 32 * 2048;
          hld = 2048;
        }
        const u16* xv = hb + (long)batch * hld + kg * 8;
        for (int ks = kh * 32; ks < kh * 32 + 32; ks += 8) {
          uint4 bv[8]; short8 av[8];
#pragma unroll
          for (int uu = 0; uu < 8; ++uu)
            bv[uu] = *(const uint4*)(xv + (long)(ks + uu) * 32);
#pragma unroll
          for (int uu = 0; uu < 8; ++uu)
            av[uu] = *(const short8*)&Wl[((rt * 64 + ks + uu) * 64 + l) * 8];
#pragma unroll
          for (int uu = 0; uu < 8; ++uu)
            acc = __builtin_amdgcn_mfma_f32_16x16x32_bf16(av[uu], *(short8*)&bv[uu], acc, 0, 0, 0);
        }
      }
      if (kh) *(f32x4*)redp = acc;
      __syncthreads();
      if (kh == 0) {
        f32x4 o = *(f32x4*)redp;
        float g0 = acc[0] + o[0] + bi0 + bf2f(xv4.x);
        float g1 = acc[1] + o[1] + bi1 + bf2f(xv4.y);
        float g2 = acc[2] + o[2] + bi2 + bf2f(xv4.z);
        float g3 = acc[3] + o[3] + bi3 + bf2f(xv4.w);
        float iv = sigf(g0), fv = sigf(g1), gv = tanhf(g2), ov = sigf(g3);
        float c = fv * creg + iv * gv;
        creg = c;
        float h = ov * tanhf(c);
        hstage[batch][rt * 4 + kg] = f2bf(h);
        if (A.layer == 1 && s == 63) A.htb[batch * 4096 + dir * 2048 + jout] = h;
      }
      __syncthreads();
      if (tid < 32) {
        uv4 v = *(const uv4*)&hstage[tid][0];
        u16* dst;
        if (A.layer == 0) dst = &A.y0b[((long)tt * 32 + tid) * 4096 + dir * 2048 + j0];
        else dst = &A.h1a[dir][((long)s * 32 + tid) * 2048 + j0];
        cstore16(dst, v);
      }
      if (kh == 0 && s < 63) {
        int ttn = dir ? 62 - s : s + 1;
        xv4 = *(const ushort4*)(xp + ((((long)ttn * 256 + blockIdx.x) * 32 + batch) * 32)
                                + (rt * 4 + kg) * 4);
      }
    }
  }
}

// ---------------- H=1024 cell (round-13 structure) ----------------
__device__ __forceinline__ void stage_w1024(u16* Wl, int m, const u16* W, int j0, int tid) {
  for (int e = tid; e < 2048; e += 512) {
    int kh = e >> 10, s = (e >> 6) & 15, el = e & 63;
    int tr = el & 15;
    long gr = (long)(tr & 3) * 1024 + j0 + (tr >> 2);
    *(uint4*)&Wl[(((m * 2 + kh) * 16 + s) * 64 + el) * 8] =
        *(const uint4*)&W[gr * 1024 + kh * 512 + (el >> 4) * 8 + s * 32];
  }
}

__device__ __forceinline__ void cell1024_lds(
    const u16* Wl, int m0, int m1,
    int j0, int tid, float* red, u16* hstage,
    const u16* X0, long x0ld,
    const u16* X1, long x1ld,
    float xg0, float xg1, float xg2, float xg3,
    float b0, float b1, float b2, float b3,
    float co, float* crp,
    u16* hout, long hld, float* houtf, long hfld) {
  const int w = tid >> 6, l = tid & 63;
  const int bh = w & 1, kh = w >> 1;
  const int kg = l >> 4;
  const int koff = kh * 256 + kg * 8;
  const int batch = bh * 16 + (l & 15);
  const int sbase = (kh >> 1) * 16 + (kh & 1) * 8;
  const int jout = j0 + kg;
  f32x4 acc = {0.f, 0.f, 0.f, 0.f};
  if (X0) {
    const u16* xpt = X0 + (long)batch * x0ld + koff;
    const int sb = m0 * 32 + sbase;
    uint4 bv[8]; short8 av[8];
#pragma unroll
    for (int uu = 0; uu < 8; ++uu) bv[uu] = *(const uint4*)(xpt + (long)uu * 32);
#pragma unroll
    for (int uu = 0; uu < 8; ++uu) av[uu] = *(const short8*)&Wl[((sb + uu) * 64 + l) * 8];
#pragma unroll
    for (int uu = 0; uu < 8; ++uu)
      acc = __builtin_amdgcn_mfma_f32_16x16x32_bf16(av[uu], *(short8*)&bv[uu], acc, 0, 0, 0);
  }
  if (X1) {
    const u16* xpt = X1 + (long)batch * x1ld + koff;
    const int sb = m1 * 32 + sbase;
    uint4 bv[8]; short8 av[8];
#pragma unroll
    for (int uu = 0; uu < 8; ++uu) bv[uu] = *(const uint4*)(xpt + (long)uu * 32);
#pragma unroll
    for (int uu = 0; uu < 8; ++uu) av[uu] = *(const short8*)&Wl[((sb + uu) * 64 + l) * 8];
#pragma unroll
    for (int uu = 0; uu < 8; ++uu)
      acc = __builtin_amdgcn_mfma_f32_16x16x32_bf16(av[uu], *(short8*)&bv[uu], acc, 0, 0, 0);
  }
  if (kh) *(f32x4*)&red[((kh - 1) * 2 + bh) * 256 + l * 4] = acc;
  __syncthreads();
  if (kh == 0) {
#pragma unroll
    for (int p = 0; p < 3; ++p) {
      f32x4 o = *(f32x4*)&red[(p * 2 + bh) * 256 + l * 4];
      acc[0] += o[0]; acc[1] += o[1]; acc[2] += o[2]; acc[3] += o[3];
    }
    float g0 = acc[0] + b0 + xg0;
    float g1 = acc[1] + b1 + xg1;
    float g2 = acc[2] + b2 + xg2;
    float g3 = acc[3] + b3 + xg3;
    float iv = sigf(g0), fv = sigf(g1), gv = tanhf(g2), ov = sigf(g3);
    float c = fv * co + iv * gv;
    *crp = c;
    float h = ov * tanhf(c);
    hstage[batch * 4 + kg] = f2bf(h);
    if (houtf) houtf[(long)batch * hfld + jout] = h;
  }
  __syncthreads();
  if (tid < 32) {
    uv2 v = *(const uv2*)&hstage[tid * 4];
    cstore8(&hout[(long)tid * hld + j0], v);
  }
}

// ---------------- persistent conductor ----------------
struct CondArgs {
  const u16 *c0h, *c1w, *c1h, *tvecb;
  const float* tvec;
  u16 *yc0b, *embb;
  float* embf;
  const float *b0i, *b0h, *b1i, *b1h;
  unsigned* bar;
};
__global__ __launch_bounds__(512) void cond_coop(CondArgs A) {
  __shared__ u16 Wl[3 * 32 * 512];
  __shared__ __align__(16) float red[6 * 256];
  __shared__ __align__(16) u16 hstage[128];
  const int j0 = blockIdx.x * 4;
  const int tid = threadIdx.x;
  const int w = tid >> 6, l = tid & 63;
  const int bh = w & 1;
  const int jout = j0 + (l >> 4);
  const int batch = bh * 16 + (l & 15);
  stage_w1024(Wl, 0, A.c0h, j0, tid);
  stage_w1024(Wl, 1, A.c1w, j0, tid);
  stage_w1024(Wl, 2, A.c1h, j0, tid);
  const float cb00 = A.b0i[jout] + A.b0h[jout];
  const float cb01 = A.b0i[1024 + jout] + A.b0h[1024 + jout];
  const float cb02 = A.b0i[2048 + jout] + A.b0h[2048 + jout];
  const float cb03 = A.b0i[3072 + jout] + A.b0h[3072 + jout];
  const float cb10 = A.b1i[jout] + A.b1h[jout];
  const float cb11 = A.b1i[1024 + jout] + A.b1h[1024 + jout];
  const float cb12 = A.b1i[2048 + jout] + A.b1h[2048 + jout];
  const float cb13 = A.b1i[3072 + jout] + A.b1h[3072 + jout];
  const float c0init = A.tvec[2048 + (long)batch * 4096 + jout];
  const float c1init = A.tvec[3072 + (long)batch * 4096 + jout];
  __syncthreads();
  float cr0 = c0init, cr1 = c1init;
  int bi = 0;
  for (int u = 0; u < NU; ++u) {
    cell1024_lds(Wl, 0, -1, j0, tid, red, hstage,
                 u ? A.yc0b + (long)(u - 1) * 32 * 1024 : A.tvecb, u ? 1024 : 4096,
                 nullptr, 0,
                 0.f, 0.f, 0.f, 0.f,
                 cb00, cb01, cb02, cb03,
                 cr0, &cr0,
                 A.yc0b + (long)u * 32 * 1024, 1024, nullptr, 0);
    gbar(A.bar + (long)(bi++) * BSTRIDE);
    cell1024_lds(Wl, 1, 2, j0, tid, red, hstage,
                 A.yc0b + (long)u * 32 * 1024, 1024,
                 u ? A.embb + (long)(u - 1) * 32 * 1024 : A.tvecb + 1024, u ? 1024 : 4096,
                 0.f, 0.f, 0.f, 0.f,
                 cb10, cb11, cb12, cb13,
                 cr1, &cr1,
                 A.embb + (long)u * 32 * 1024, 1024, A.embf + (long)u * 32 * 1024, 1024);
    if (u < NU - 1) gbar(A.bar + (long)(bi++) * BSTRIDE);
  }
}

// ---------------- persistent hierarchical decoder ----------------
struct DecArgs {
  const u16 *d1h, *wfuse, *d2w, *d2h, *xeb, *sallb;
  const float* sall;
  u16 *dh1all, *dh2all;
  const float *bfuse, *b1h, *b2i, *b2h;
  unsigned* bar;
};
__global__ __launch_bounds__(512) void dec_coop(DecArgs A) {
  __shared__ u16 Wl[4 * 32 * 512];
  __shared__ __align__(16) float red[6 * 256];
  __shared__ __align__(16) u16 hstage[128];
  const int j0 = blockIdx.x * 4;
  const int tid = threadIdx.x;
  const int w = tid >> 6, l = tid & 63;
  const int bh = w & 1;
  const int kg = l >> 4;
  const int jout = j0 + kg;
  const int batch = bh * 16 + (l & 15);
  stage_w1024(Wl, 0, A.d1h, j0, tid);
  stage_w1024(Wl, 1, A.wfuse, j0, tid);
  stage_w1024(Wl, 2, A.d2w, j0, tid);
  stage_w1024(Wl, 3, A.d2h, j0, tid);
  const float b1z0 = A.b1h[jout], b1z1 = A.b1h[1024 + jout],
              b1z2 = A.b1h[2048 + jout], b1z3 = A.b1h[3072 + jout];
  const float b1n0 = b1z0 + A.bfuse[jout], b1n1 = b1z1 + A.bfuse[1024 + jout],
              b1n2 = b1z2 + A.bfuse[2048 + jout], b1n3 = b1z3 + A.bfuse[3072 + jout];
  const float b20 = A.b2i[jout] + A.b2h[jout];
  const float b21 = A.b2i[1024 + jout] + A.b2h[1024 + jout];
  const float b22 = A.b2i[2048 + jout] + A.b2h[2048 + jout];
  const float b23 = A.b2i[3072 + jout] + A.b2h[3072 + jout];
  const u16* xqb = A.xeb + (long)blockIdx.x * 128 * 16;
  ushort4 xq4 = *(const ushort4*)(xqb + (long)batch * 16 + kg * 4);
  float con1 = A.sall[(long)batch * 4096 + 2048 + jout];
  float con2 = A.sall[(long)batch * 4096 + 3072 + jout];
  __syncthreads();
  float cr1 = 0.f, cr2 = 0.f;
  int bi = 0;
  for (int t = 0; t < TT; ++t) {
    const int u = t >> 4, sg = t & 15;
    if (sg == 0) { cr1 = con1; cr2 = con2; }
    cell1024_lds(Wl, 0, 1, j0, tid, red, hstage,
                 sg ? A.dh1all + (long)(t - 1) * 32 * 1024 : A.sallb + (long)u * 32 * 4096,
                 sg ? 1024 : 4096,
                 t ? A.dh2all + (long)(t - 1) * 32 * 1024 : nullptr, 1024,
                 bf2f(xq4.x), bf2f(xq4.y), bf2f(xq4.z), bf2f(xq4.w),
                 t ? b1n0 : b1z0, t ? b1n1 : b1z1, t ? b1n2 : b1z2, t ? b1n3 : b1z3,
                 cr1, &cr1,
                 A.dh1all + (long)t * 32 * 1024, 1024, nullptr, 0);
    gbar(A.bar + (long)(bi++) * BSTRIDE);
    cell1024_lds(Wl, 2, 3, j0, tid, red, hstage,
                 A.dh1all + (long)t * 32 * 1024, 1024,
                 sg ? A.dh2all + (long)(t - 1) * 32 * 1024 : A.sallb + (long)u * 32 * 4096 + 1024,
                 sg ? 1024 : 4096,
                 0.f, 0.f, 0.f, 0.f,
                 b20, b21, b22, b23,
                 cr2, &cr2,
                 A.dh2all + (long)t * 32 * 1024, 1024, nullptr, 0);
    if (sg == 15 && u < 3) {
      xq4 = *(const ushort4*)(xqb + (long)(u + 1) * 32 * 16 + (long)batch * 16 + kg * 4);
      con1 = A.sall[(long)(u + 1) * 32 * 4096 + (long)batch * 4096 + 2048 + jout];
      con2 = A.sall[(long)(u + 1) * 32 * 4096 + (long)batch * 4096 + 3072 + jout];
    }
    if (t < TT - 1) gbar(A.bar + (long)(bi++) * BSTRIDE);
  }
}

// ---------------- final p = dh2all @ w4^T + b4 -> out ----------------
__global__ __launch_bounds__(256) void proj_all(const u16* __restrict__ dh2all,
                                                const u16* __restrict__ w4b,
                                                const float* __restrict__ b4,
                                                float* __restrict__ out) {
  __shared__ u16 hs[8 * 1024];
  const int r0 = blockIdx.x * 8;
  for (int e = threadIdx.x; e < 1024; e += 256)
    ((uint4*)hs)[e] = ((const uint4*)(dh2all + (long)r0 * 1024))[e];
  __syncthreads();
  for (int o = threadIdx.x; o < 8 * INPW; o += 256) {
    int rr = o / INPW, n = o % INPW;
    const u16* wr = w4b + (long)n * 1024;
    const u16* hr = hs + rr * 1024;
    float s = 0.0f;
    for (int k = 0; k < 1024; ++k) s += bf2f(hr[k]) * bf2f(wr[k]);
    int row = r0 + rr;
    int tt = row >> 5, b = row & 31;
    out[((long)b * TT + tt) * INPW + n] = s + b4[n];
  }
}

// =====================================================================
extern "C" void kernel_launch(void* const* d_in, const int* in_sizes, int n_in,
                              void* d_out, int out_size, void* d_ws, size_t ws_size,
                              hipStream_t stream) {
  (void)in_sizes; (void)n_in; (void)out_size;
  const float* x        = (const float*)d_in[0];
  const float* eps      = (const float*)d_in[1];
  const float* e0f_wih  = (const float*)d_in[2];
  const float* e0f_whh  = (const float*)d_in[3];
  const float* e0f_bih  = (const float*)d_in[4];
  const float* e0f_bhh  = (const float*)d_in[5];
  const float* e0b_wih  = (const float*)d_in[6];
  const float* e0b_whh  = (const float*)d_in[7];
  const float* e0b_bih  = (const float*)d_in[8];
  const float* e0b_bhh  = (const float*)d_in[9];
  const float* e1f_wih  = (const float*)d_in[10];
  const float* e1f_whh  = (const float*)d_in[11];
  const float* e1f_bih  = (const float*)d_in[12];
  const float* e1f_bhh  = (const float*)d_in[13];
  const float* e1b_wih  = (const float*)d_in[14];
  const float* e1b_whh  = (const float*)d_in[15];
  const float* e1b_bih  = (const float*)d_in[16];
  const float* e1b_bhh  = (const float*)d_in[17];
  const float* wm  = (const float*)d_in[18];
  const float* bm  = (const float*)d_in[19];
  const float* wsw = (const float*)d_in[20];
  const float* bsv = (const float*)d_in[21];
  const float* w2  = (const float*)d_in[22];
  const float* b2  = (const float*)d_in[23];
  const float* c0_whh = (const float*)d_in[25];
  const float* c0_bih = (const float*)d_in[26];
  const float* c0_bhh = (const float*)d_in[27];
  const float* c1_wih = (const float*)d_in[28];
  const float* c1_whh = (const float*)d_in[29];
  const float* c1_bih = (const float*)d_in[30];
  const float* c1_bhh = (const float*)d_in[31];
  const float* w3 = (const float*)d_in[32];
  const float* b3 = (const float*)d_in[33];
  const float* d1_wih = (const float*)d_in[34];
  const float* d1_whh = (const float*)d_in[35];
  const float* d1_bih = (const float*)d_in[36];
  const float* d1_bhh = (const float*)d_in[37];
  const float* d2_wih = (const float*)d_in[38];
  const float* d2_whh = (const float*)d_in[39];
  const float* d2_bih = (const float*)d_in[40];
  const float* d2_bhh = (const float*)d_in[41];
  const float* w4 = (const float*)d_in[42];
  const float* b4 = (const float*)d_in[43];

  float* out = (float*)d_out;
  float* zm_out = out + (size_t)BB * TT * INPW;
  float* zs_out = zm_out + BB * NZ;

  char* wbase = (char*)d_ws;
  size_t cur = 0;
  auto AL = [&](size_t bytes) -> void* {
    void* p = wbase + cur;
    cur = (cur + bytes + 255) & ~(size_t)255;
    return p;
  };
  u16* xb    = (u16*)AL(2048L * 128 * 2);
  u16* e0wf  = (u16*)AL(8192L * 128 * 2);
  u16* e0wb  = (u16*)AL(8192L * 128 * 2);
  u16* e0hf  = (u16*)AL(8192L * 2048 * 2);
  u16* e0hb  = (u16*)AL(8192L * 2048 * 2);
  u16* e1wf  = (u16*)AL(8192L * 4096 * 2);
  u16* e1wb  = (u16*)AL(8192L * 4096 * 2);
  u16* e1hf  = (u16*)AL(8192L * 2048 * 2);
  u16* e1hb  = (u16*)AL(8192L * 2048 * 2);
  u16* c0h   = (u16*)AL(4096L * 1024 * 2);
  u16* c1w   = (u16*)AL(4096L * 1024 * 2);
  u16* c1h   = (u16*)AL(4096L * 1024 * 2);
  u16* d1we  = (u16*)AL(4096L * 1024 * 2);
  u16* d1wp  = (u16*)AL(4096L * 128 * 2);
  u16* d1h   = (u16*)AL(4096L * 1024 * 2);
  u16* d2w   = (u16*)AL(4096L * 1024 * 2);
  u16* d2h   = (u16*)AL(4096L * 1024 * 2);
  u16* w4b   = (u16*)AL(90L * 1024 * 2);
  u16* w4tb  = (u16*)AL(1024L * 128 * 2);
  u16* wfuse = (u16*)AL(4096L * 1024 * 2);
  float* bfuse = (float*)AL(4096L * 4);
  float* pb_e0f = (float*)AL(8192L * 4);
  float* pb_e0b = (float*)AL(8192L * 4);
  float* pb_e1f = (float*)AL(8192L * 4);
  float* pb_e1b = (float*)AL(8192L * 4);
  float* pb_d1  = (float*)AL(4096L * 4);
  u16* xp0f  = (u16*)AL(2048L * 8192 * 2);
  u16* xp0b  = (u16*)AL(2048L * 8192 * 2);
  u16* y0b   = (u16*)AL(2048L * 4096 * 2);
  u16* xp1f  = (u16*)AL(2048L * 8192 * 2);
  u16* xp1b  = (u16*)AL(2048L * 8192 * 2);
  u16* h1af  = (u16*)AL(64L * 32 * 2048 * 2);
  u16* h1ab  = (u16*)AL(64L * 32 * 2048 * 2);
  u16* tvecb = (u16*)AL(32L * 4096 * 2);
  u16* yc0b  = (u16*)AL(4L * 32 * 1024 * 2);
  u16* embb  = (u16*)AL(4L * 32 * 1024 * 2);
  u16* sallb = (u16*)AL(128L * 4096 * 2);
  u16* xeb   = (u16*)AL(128L * 4096 * 2);
  u16* dh1all= (u16*)AL(64L * 32 * 1024 * 2);
  u16* dh2all= (u16*)AL(64L * 32 * 1024 * 2);
  float* htb  = (float*)AL(32L * 4096 * 4);
  float* zbuf = (float*)AL(32L * 512 * 4);
  float* tvec = (float*)AL(32L * 4096 * 4);
  float* embf = (float*)AL(128L * 1024 * 4);
  float* sall = (float*)AL(128L * 4096 * 4);
  unsigned* barp = (unsigned*)AL(400L * BSTRIDE * 4);
  if (cur > ws_size) return;

  unsigned* bar_enc0 = barp;
  unsigned* bar_enc1 = barp + 128L * BSTRIDE;
  unsigned* bar_cond = barp + 256L * BSTRIDE;
  unsigned* bar_dec  = barp + 264L * BSTRIDE;

  // ---- conversions (fused) ----
  {
    CvtJobs J{};
    int c = 0;
    auto add = [&](const float* s, u16* d, long n) { J.s[c] = s; J.d[c] = d; J.n[c] = n; ++c; };
    add(e0f_whh, e0hf, 8192L * 2048);
    add(e0b_whh, e0hb, 8192L * 2048);
    add(e1f_whh, e1hf, 8192L * 2048);
    add(e1b_whh, e1hb, 8192L * 2048);
    add(c0_whh, c0h, 4096L * 1024);
    add(c1_wih, c1w, 4096L * 1024);
    add(c1_whh, c1h, 4096L * 1024);
    add(d1_whh, d1h, 4096L * 1024);
    add(d2_wih, d2w, 4096L * 1024);
    add(d2_whh, d2h, 4096L * 1024);
    add(w4, w4b, 90L * 1024);
    J.cnt = c;
    cvt_multi<<<dim3(2048), 256, 0, stream>>>(J);
  }
  cvt_permrow<<<dim3(1, 8192), 128, 0, stream>>>(e0f_wih, 90, 90, e0wf, 128, 2048);
  cvt_permrow<<<dim3(1, 8192), 128, 0, stream>>>(e0b_wih, 90, 90, e0wb, 128, 2048);
  cvt_permrow<<<dim3(16, 8192), 256, 0, stream>>>(e1f_wih, 4096, 4096, e1wf, 4096, 2048);
  cvt_permrow<<<dim3(16, 8192), 256, 0, stream>>>(e1b_wih, 4096, 4096, e1wb, 4096, 2048);
  cvt_permrow<<<dim3(4, 4096), 256, 0, stream>>>(d1_wih, 1114, 1024, d1we, 1024, 1024);
  {
    BPJobs J{};
    J.s[0] = e0f_bih; J.d[0] = pb_e0f; J.H[0] = 2048;
    J.s[1] = e0b_bih; J.d[1] = pb_e0b; J.H[1] = 2048;
    J.s[2] = e1f_bih; J.d[2] = pb_e1f; J.H[2] = 2048;
    J.s[3] = e1b_bih; J.d[3] = pb_e1b; J.H[3] = 2048;
    J.s[4] = d1_bih;  J.d[4] = pb_d1;  J.H[4] = 1024;
    J.cnt = 5;
    bias_perm5<<<dim3(32), 256, 0, stream>>>(J);
  }
  cvt_pad<<<dim3(1, 4096), 128, 0, stream>>>(d1_wih + 1024, 1114, 90, d1wp, 128, 4096);
  xcvt<<<dim3(2048), 128, 0, stream>>>(x, xb);
  w4t_k<<<dim3(1024), 128, 0, stream>>>(w4, w4tb);
  bfuse_k<<<dim3(16), 256, 0, stream>>>(d1_wih, b4, bfuse);
  hipMemsetAsync(barp, 0, 400L * BSTRIDE * 4, stream);

  gemm_bf<<<dim3(256), 256, 0, stream>>>(d1wp, 128, w4tb, 128, nullptr, wfuse, 1024, 128, 0, 32, 8);
  gemm_bf<<<dim3(1024), 256, 0, stream>>>(xb, 128, e0wf, 128, pb_e0f, xp0f, 8192, 128, 1, 16, 64);
  gemm_bf<<<dim3(1024), 256, 0, stream>>>(xb, 128, e0wb, 128, pb_e0b, xp0b, 8192, 128, 1, 16, 64);

  // ---- encoder layer 0 ----
  {
    EncArgs ea{};
    ea.whh[0] = e0hf; ea.whh[1] = e0hb;
    ea.xp[0] = xp0f; ea.xp[1] = xp0b;
    ea.bhh[0] = e0f_bhh; ea.bhh[1] = e0b_bhh;
    ea.y0b = y0b; ea.h1a[0] = h1af; ea.h1a[1] = h1ab; ea.htb = htb;
    ea.bar = bar_enc0; ea.layer = 0;
    void* args[] = {&ea};
    (void)hipLaunchCooperativeKernel((void*)enc_coop, dim3(256), dim3(512), args, 0, stream);
  }

  gemm_bf<<<dim3(1024), 256, 0, stream>>>(y0b, 4096, e1wf, 4096, pb_e1f, xp1f, 8192, 4096, 1, 16, 64);
  gemm_bf<<<dim3(1024), 256, 0, stream>>>(y0b, 4096, e1wb, 4096, pb_e1b, xp1b, 8192, 4096, 1, 16, 64);

  // ---- encoder layer 1 ----
  {
    EncArgs ea{};
    ea.whh[0] = e1hf; ea.whh[1] = e1hb;
    ea.xp[0] = xp1f; ea.xp[1] = xp1b;
    ea.bhh[0] = e1f_bhh; ea.bhh[1] = e1b_bhh;
    ea.y0b = y0b; ea.h1a[0] = h1af; ea.h1a[1] = h1ab; ea.htb = htb;
    ea.bar = bar_enc1; ea.layer = 1;
    void* args[] = {&ea};
    (void)hipLaunchCooperativeKernel((void*)enc_coop, dim3(256), dim3(512), args, 0, stream);
  }

  // ---- latent ----
  latgemm<<<dim3(32), 256, 0, stream>>>(htb, wm, bm, zm_out, 0);
  latgemm<<<dim3(32), 256, 0, stream>>>(htb, wsw, bsv, zs_out, 2);
  zcalc_kernel<<<dim3(64), 256, 0, stream>>>(zm_out, zs_out, eps, zbuf);
  gemm128<<<dim3(1, 32), 256, 0, stream>>>(zbuf, 512, w2, 512, b2, tvec, 4096, 32, 512, 1, tvecb);

  // ---- conductor ----
  {
    CondArgs ca{};
    ca.c0h = c0h; ca.c1w = c1w; ca.c1h = c1h;
    ca.tvecb = tvecb; ca.tvec = tvec;
    ca.yc0b = yc0b; ca.embb = embb; ca.embf = embf;
    ca.b0i = c0_bih; ca.b0h = c0_bhh; ca.b1i = c1_bih; ca.b1h = c1_bhh;
    ca.bar = bar_cond;
    void* args[] = {&ca};
    (void)hipLaunchCooperativeKernel((void*)cond_coop, dim3(256), dim3(512), args, 0, stream);
  }

  // ---- decoder prep ----
  gemm128<<<dim3(1, 32), 256, 0, stream>>>(embf, 1024, w3, 1024, b3, sall, 4096, 128, 1024, 1, sallb);
  gemm_bf<<<dim3(32), 256, 0, stream>>>(embb, 1024, d1we, 1024, pb_d1, xeb, 4096, 1024, 2, 1, 32);

  // ---- hierarchical decoder ----
  {
    DecArgs da{};
    da.d1h = d1h; da.wfuse = wfuse; da.d2w = d2w; da.d2h = d2h;
    da.xeb = xeb; da.sallb = sallb; da.sall = sall;
    da.dh1all = dh1all; da.dh2all = dh2all;
    da.bfuse = bfuse; da.b1h = d1_bhh; da.b2i = d2_bih; da.b2h = d2_bhh;
    da.bar = bar_dec;
    void* args[] = {&da};
    (void)hipLaunchCooperativeKernel((void*)dec_coop, dim3(256), dim3(512), args, 0, stream);
  }

  // ---- outputs ----
  proj_all<<<dim3(256), 256, 0, stream>>>(dh2all, w4b, b4, out);
  softmax_kernel<<<dim3(BB * TT), 64, 0, stream>>>(out);
}